// Round 9
// baseline (318.680 us; speedup 1.0000x reference)
//
#include <hip/hip_runtime.h>
#include <hip/hip_bf16.h>
#include <math.h>

#ifndef __has_builtin
#define __has_builtin(x) 0
#endif
#if __has_builtin(__builtin_amdgcn_cvt_pk_fp8_f32) && __has_builtin(__builtin_amdgcn_cvt_pk_f32_fp8)
#define FP8_HW 1
#else
#include <hip/hip_fp8.h>
#endif

#define D 128
#define KVREC 384   // 128 B k (fp8 e4m3) + 256 B v (bf16)

typedef float f32x16 __attribute__((ext_vector_type(16)));
typedef float f32x2  __attribute__((ext_vector_type(2)));
typedef short bf16x8 __attribute__((ext_vector_type(8)));

// gelu tanh-approx, exact rewrite: 0.5x(1+tanh(u)) == x / (1 + e^{-2u})
__device__ __forceinline__ float gelu_fast(float x) {
    float u = 0.7978845608028654f * (x + 0.044715f * x * x * x);
    return x / (1.0f + __expf(-2.0f * u));
}

__device__ __forceinline__ unsigned short f2bf(float f) {
    union { float f; unsigned u; } x; x.f = f;
    unsigned r = x.u + 0x7fff + ((x.u >> 16) & 1);   // RNE
    return (unsigned short)(r >> 16);
}

__device__ __forceinline__ float bflo(unsigned u) { return __uint_as_float(u << 16); }
__device__ __forceinline__ float bfhi(unsigned u) { return __uint_as_float(u & 0xffff0000u); }

__device__ __forceinline__ unsigned char f2fp8(float x) {
#ifdef FP8_HW
    return (unsigned char)(__builtin_amdgcn_cvt_pk_fp8_f32(x, x, 0, false) & 0xFF);
#else
    __hip_fp8_e4m3 h(x); return (unsigned char)h.__x;
#endif
}

__device__ __forceinline__ void fp8x4d(unsigned u, float* f) {
#ifdef FP8_HW
    f32x2 lo = __builtin_amdgcn_cvt_pk_f32_fp8((int)u, false);
    f32x2 hi = __builtin_amdgcn_cvt_pk_f32_fp8((int)u, true);
    f[0] = lo[0]; f[1] = lo[1]; f[2] = hi[0]; f[3] = hi[1];
#else
    #pragma unroll
    for (int i = 0; i < 4; ++i) {
        __hip_fp8_e4m3 h; h.__x = (unsigned char)((u >> (8 * i)) & 0xFF);
        f[i] = (float)h;
    }
#endif
}

// ================= fused_pre: hist (blocks < nbE8) || prepack (last 192) =====

__global__ __launch_bounds__(256) void fused_pre_kernel(
    const int* __restrict__ rows, int* __restrict__ cnt, int nE, int n, int nbE8,
    const float* __restrict__ W0, const float* __restrict__ W1,
    const float* __restrict__ W2, unsigned short* __restrict__ F)
{
    const int bid = blockIdx.x;
    if (bid < nbE8) {
        // ---- hist: XCD-sliced (group g = bid&7 owns rows [g*n/8,(g+1)*n/8)) ----
        const int g  = bid & 7;
        const int lo = (int)(((long long)g * n) >> 3);
        const int hi = (int)(((long long)(g + 1) * n) >> 3);
        const int idx = (bid >> 3) * 1024 + threadIdx.x * 4;
        if (idx + 3 < nE) {
            int4 r4 = *reinterpret_cast<const int4*>(rows + idx);
            if (r4.x >= lo && r4.x < hi) atomicAdd(&cnt[r4.x], 1);
            if (r4.y >= lo && r4.y < hi) atomicAdd(&cnt[r4.y], 1);
            if (r4.z >= lo && r4.z < hi) atomicAdd(&cnt[r4.z], 1);
            if (r4.w >= lo && r4.w < hi) atomicAdd(&cnt[r4.w], 1);
        } else {
            for (int i = 0; i < 4; ++i)
                if (idx + i < nE) {
                    int r = rows[idx + i];
                    if (r >= lo && r < hi) atomicAdd(&cnt[r], 1);
                }
        }
    } else {
        // ---- prepack: 3 W[128][128] -> MFMA B-fragment order (bf16) ----
        int gidx = (bid - nbE8) * 256 + threadIdx.x;
        if (gidx >= 3 * 32 * 64 * 8) return;
        const int midx = gidx >> 14;
        const int idx  = gidx & 16383;
        const float* W = midx == 0 ? W0 : (midx == 1 ? W1 : W2);
        int j  = idx & 7;
        int l  = (idx >> 3) & 63;
        int kt = (idx >> 9) & 7;
        int ct = idx >> 12;
        int kk = kt * 16 + (l >> 5) * 8 + j;
        int c  = ct * 32 + (l & 31);
        F[gidx] = f2bf(W[kk * D + c]);
    }
}

// ================= scan: block sums, then write (with inline boff re-scan) ===

__global__ __launch_bounds__(256) void scan_bsum_kernel(
    const int* __restrict__ cnt, int* __restrict__ bsum, int n)
{
    __shared__ int s[256];
    const int t = threadIdx.x;
    const int base = blockIdx.x * 1024 + t * 4;
    int sum = 0;
    if (base + 3 < n) {
        int4 c4 = *reinterpret_cast<const int4*>(cnt + base);
        sum = c4.x + c4.y + c4.z + c4.w;
    } else {
        for (int i = 0; i < 4; ++i) if (base + i < n) sum += cnt[base + i];
    }
    s[t] = sum;
    __syncthreads();
    #pragma unroll
    for (int off = 128; off > 0; off >>= 1) {
        if (t < off) s[t] += s[t + off];
        __syncthreads();
    }
    if (t == 0) bsum[blockIdx.x] = s[0];
}

// Each block re-scans bsum[0..nb) in LDS, then writes rowptr AND cur.
__global__ __launch_bounds__(256) void scan_write2_kernel(
    const int* __restrict__ cnt, const int* __restrict__ bsum, int nb,
    int* __restrict__ rowptr, int* __restrict__ cur, int n)
{
    __shared__ int s[256];
    const int t = threadIdx.x;

    // phase A: inclusive scan of block sums
    s[t] = (t < nb) ? bsum[t] : 0;
    __syncthreads();
    #pragma unroll
    for (int off = 1; off < 256; off <<= 1) {
        int v = (t >= off) ? s[t - off] : 0;
        __syncthreads();
        s[t] += v;
        __syncthreads();
    }
    const int boffv = (blockIdx.x > 0) ? s[blockIdx.x - 1] : 0;  // exclusive
    const int total = s[255];
    if (blockIdx.x == 0 && t == 0) rowptr[n] = total;
    __syncthreads();   // everyone has boffv; safe to reuse s

    // phase B: per-1024-chunk scan
    const int base = blockIdx.x * 1024 + t * 4;
    int c[4] = {0, 0, 0, 0};
    if (base + 3 < n) {
        int4 c4 = *reinterpret_cast<const int4*>(cnt + base);
        c[0] = c4.x; c[1] = c4.y; c[2] = c4.z; c[3] = c4.w;
    } else {
        for (int i = 0; i < 4; ++i) if (base + i < n) c[i] = cnt[base + i];
    }
    const int tsum = c[0] + c[1] + c[2] + c[3];
    s[t] = tsum;
    __syncthreads();
    #pragma unroll
    for (int off = 1; off < 256; off <<= 1) {
        int v = (t >= off) ? s[t - off] : 0;
        __syncthreads();
        s[t] += v;
        __syncthreads();
    }
    int run = boffv + s[t] - tsum;
    int w0 = run;
    int w1 = run + c[0];
    int w2 = w1 + c[1];
    int w3 = w2 + c[2];
    if (base + 3 < n) {
        int4 wv = make_int4(w0, w1, w2, w3);
        *reinterpret_cast<int4*>(rowptr + base) = wv;
        *reinterpret_cast<int4*>(cur + base)    = wv;
    } else {
        int w[4] = {w0, w1, w2, w3};
        for (int i = 0; i < 4; ++i)
            if (base + i < n) { rowptr[base + i] = w[i]; cur[base + i] = w[i]; }
    }
}

// ========== fused_mid: scatter || proj_q || proj_kv (block-range branch) =====
// NO LDS anywhere in this kernel: proj A-fragments are loaded directly from
// global X (f32, two float4 per kt) and converted in-register. The wave's
// 16 KB row-set is L1-resident across the kt loop, so net traffic matches the
// old LDS staging, while scatter blocks regain full occupancy (R8: 34.8 KB
// static LDS capped the whole fused kernel at 4 blocks/CU = 20% occupancy).

__global__ __launch_bounds__(256) void fused_mid_kernel(
    // scatter
    const int* __restrict__ rows, const int* __restrict__ cols,
    int* __restrict__ cur, int* __restrict__ colsorted, int nE, int nbE8,
    // proj
    const float* __restrict__ Xq, const float* __restrict__ Xm,
    const unsigned short* __restrict__ Fq, const float* __restrict__ bq,
    unsigned short* __restrict__ qout,
    const unsigned short* __restrict__ Fk, const float* __restrict__ bk,
    const unsigned short* __restrict__ Fv, const float* __restrict__ bv,
    unsigned char* __restrict__ kv,
    int n, int m, int nbQ)
{
    const int bid = blockIdx.x;
    const int tid = threadIdx.x;

    if (bid < nbE8) {
        // ---- scatter (XCD-sliced row ranges; cur pre-initialized to rowptr) ----
        const int g  = bid & 7;
        const int lo = (int)(((long long)g * n) >> 3);
        const int hi = (int)(((long long)(g + 1) * n) >> 3);
        const int idx = (bid >> 3) * 1024 + tid * 4;
        if (idx + 3 < nE) {
            int4 r4 = *reinterpret_cast<const int4*>(rows + idx);
            int4 c4 = *reinterpret_cast<const int4*>(cols + idx);
            if (r4.x >= lo && r4.x < hi) colsorted[atomicAdd(&cur[r4.x], 1)] = c4.x;
            if (r4.y >= lo && r4.y < hi) colsorted[atomicAdd(&cur[r4.y], 1)] = c4.y;
            if (r4.z >= lo && r4.z < hi) colsorted[atomicAdd(&cur[r4.z], 1)] = c4.z;
            if (r4.w >= lo && r4.w < hi) colsorted[atomicAdd(&cur[r4.w], 1)] = c4.w;
        } else {
            for (int i = 0; i < 4; ++i)
                if (idx + i < nE) {
                    int r = rows[idx + i];
                    if (r >= lo && r < hi)
                        colsorted[atomicAdd(&cur[r], 1)] = cols[idx + i];
                }
        }
        return;
    }

    const int pb = bid - nbE8;
    const bool isQ = pb < nbQ;
    const int row0 = (isQ ? pb : pb - nbQ) * 128;
    const int nn   = isQ ? n : m;
    const float* X = isQ ? Xq : Xm;

    const int l = tid & 63;
    const int w = tid >> 6;
    int arow = row0 + w * 32 + (l & 31);
    if (arow >= nn) arow = nn - 1;              // clamp; stores are guarded

    // A-fragments direct from global: lane holds X[arow][kt*16+(l>>5)*8 + j]
    const float* Xrow = X + (size_t)arow * D + (l >> 5) * 8;
    bf16x8 af[8];
    #pragma unroll
    for (int kt = 0; kt < 8; ++kt) {
        float4 a0 = *reinterpret_cast<const float4*>(Xrow + kt * 16);
        float4 a1 = *reinterpret_cast<const float4*>(Xrow + kt * 16 + 4);
        bf16x8 f;
        f[0] = (short)f2bf(a0.x); f[1] = (short)f2bf(a0.y);
        f[2] = (short)f2bf(a0.z); f[3] = (short)f2bf(a0.w);
        f[4] = (short)f2bf(a1.x); f[5] = (short)f2bf(a1.y);
        f[6] = (short)f2bf(a1.z); f[7] = (short)f2bf(a1.w);
        af[kt] = f;
    }

    if (isQ) {
        #pragma unroll
        for (int ct = 0; ct < 4; ++ct) {
            f32x16 acc = {};
            #pragma unroll
            for (int kt = 0; kt < 8; ++kt) {
                bf16x8 bfr = *reinterpret_cast<const bf16x8*>(Fq + ((size_t)((ct * 8 + kt) * 64 + l) * 8));
                acc = __builtin_amdgcn_mfma_f32_32x32x16_bf16(af[kt], bfr, acc, 0, 0, 0);
            }
            const int col = ct * 32 + (l & 31);
            const float bb = bq[col];
            #pragma unroll
            for (int reg = 0; reg < 16; ++reg) {
                int r  = (reg & 3) + 8 * (reg >> 2) + 4 * (l >> 5);
                int gr = row0 + w * 32 + r;
                if (gr < nn)
                    qout[(size_t)gr * D + col] = f2bf(gelu_fast(acc[reg] + bb));
            }
        }
    } else {
        for (int mat = 0; mat < 2; ++mat) {
            const unsigned short* F = mat ? Fv : Fk;
            const float* bias       = mat ? bv : bk;
            #pragma unroll
            for (int ct = 0; ct < 4; ++ct) {
                f32x16 acc = {};
                #pragma unroll
                for (int kt = 0; kt < 8; ++kt) {
                    bf16x8 bfr = *reinterpret_cast<const bf16x8*>(F + ((size_t)((ct * 8 + kt) * 64 + l) * 8));
                    acc = __builtin_amdgcn_mfma_f32_32x32x16_bf16(af[kt], bfr, acc, 0, 0, 0);
                }
                const int col = ct * 32 + (l & 31);
                const float bb = bias[col];
                #pragma unroll
                for (int reg = 0; reg < 16; ++reg) {
                    int r  = (reg & 3) + 8 * (reg >> 2) + 4 * (l >> 5);
                    int gr = row0 + w * 32 + r;
                    if (gr < nn) {
                        unsigned char* rec = kv + (size_t)gr * KVREC;
                        float val = gelu_fast(acc[reg] + bb);
                        if (mat == 0)
                            rec[col] = f2fp8(val);
                        else
                            reinterpret_cast<unsigned short*>(rec + 128)[col] = f2bf(val);
                    }
                }
            }
        }
    }
}

// ---- aggregation: one wave per row, 4 edges in flight (16 lanes each) ----
// q bf16 [n][128]; kv record [m][384]: k fp8 (128 B) then v bf16 (256 B)
__global__ __launch_bounds__(256) void agg_kernel(
    const unsigned short* __restrict__ q, const unsigned char* __restrict__ kv,
    const int* __restrict__ rowptr, const int* __restrict__ colsorted,
    float* __restrict__ out, int n)
{
    const int wave = (blockIdx.x * 256 + threadIdx.x) >> 6;
    if (wave >= n) return;
    const int lane = threadIdx.x & 63;
    const int sub  = lane >> 4;
    const int l    = lane & 15;

    const uint4 qa = *reinterpret_cast<const uint4*>(q + (size_t)wave * D + l * 8);
    float qf[8];
    qf[0] = bflo(qa.x); qf[1] = bfhi(qa.x);
    qf[2] = bflo(qa.y); qf[3] = bfhi(qa.y);
    qf[4] = bflo(qa.z); qf[5] = bfhi(qa.z);
    qf[6] = bflo(qa.w); qf[7] = bfhi(qa.w);

    float acc[8] = {0.f,0.f,0.f,0.f,0.f,0.f,0.f,0.f};
    const int start = rowptr[wave], end = rowptr[wave + 1];

    #pragma unroll 2
    for (int i = start + sub; i < end; i += 4) {
        const int c = colsorted[i];
        const unsigned char* rec = kv + (size_t)c * KVREC;
        const uint2 kb = *reinterpret_cast<const uint2*>(rec + l * 8);
        const uint4 vb = *reinterpret_cast<const uint4*>(rec + 128 + l * 16);

        float kf[8];
        fp8x4d(kb.x, kf); fp8x4d(kb.y, kf + 4);

        float dot = 0.0f;
        #pragma unroll
        for (int j = 0; j < 8; ++j) dot = fmaf(qf[j], kf[j], dot);
        dot += __shfl_xor(dot, 1);
        dot += __shfl_xor(dot, 2);
        dot += __shfl_xor(dot, 4);
        dot += __shfl_xor(dot, 8);
        const float coef = 1.0f / (1.0f + __expf(-dot * 0.08838834764831845f));

        acc[0] = fmaf(coef, bflo(vb.x), acc[0]);
        acc[1] = fmaf(coef, bfhi(vb.x), acc[1]);
        acc[2] = fmaf(coef, bflo(vb.y), acc[2]);
        acc[3] = fmaf(coef, bfhi(vb.y), acc[3]);
        acc[4] = fmaf(coef, bflo(vb.z), acc[4]);
        acc[5] = fmaf(coef, bfhi(vb.z), acc[5]);
        acc[6] = fmaf(coef, bflo(vb.w), acc[6]);
        acc[7] = fmaf(coef, bfhi(vb.w), acc[7]);
    }

    #pragma unroll
    for (int j = 0; j < 8; ++j) {
        acc[j] += __shfl_xor(acc[j], 16);
        acc[j] += __shfl_xor(acc[j], 32);
    }

    if (sub == 0) {
        float* op = out + (size_t)wave * D + l * 8;
        float4 o0 = {acc[0], acc[1], acc[2], acc[3]};
        float4 o1 = {acc[4], acc[5], acc[6], acc[7]};
        *reinterpret_cast<float4*>(op)     = o0;
        *reinterpret_cast<float4*>(op + 4) = o1;
    }
}

extern "C" void kernel_launch(void* const* d_in, const int* in_sizes, int n_in,
                              void* d_out, int out_size, void* d_ws, size_t ws_size,
                              hipStream_t stream) {
    const float* query  = (const float*)d_in[0];
    const float* memory = (const float*)d_in[1];
    const float* Wq     = (const float*)d_in[2];
    const float* bq     = (const float*)d_in[3];
    const float* Wk     = (const float*)d_in[4];
    const float* bk     = (const float*)d_in[5];
    const float* Wv     = (const float*)d_in[6];
    const float* bv     = (const float*)d_in[7];
    const int*   erows  = (const int*)d_in[8];
    const int*   ecols  = (const int*)d_in[9];

    const int n  = in_sizes[0] / D;   // 100000
    const int m  = in_sizes[1] / D;   // 100000
    const int nE = in_sizes[8];       // 1600000

    char* base = (char*)d_ws;
    size_t off = 0;
    auto carve = [&](size_t bytes) -> char* {
        char* p = base + off;
        off = (off + bytes + 255) & ~(size_t)255;
        return p;
    };
    unsigned short* q   = (unsigned short*)carve((size_t)n * D * sizeof(unsigned short));
    unsigned char*  kv  = (unsigned char*) carve((size_t)m * KVREC);
    unsigned short* F   = (unsigned short*)carve(3 * 32 * 64 * 8 * sizeof(unsigned short));
    int*   rowptr    = (int*)carve((size_t)(n + 1) * sizeof(int));
    int*   cnt       = (int*)carve((size_t)(n + 1) * sizeof(int));
    int*   cur       = (int*)carve((size_t)(n + 1) * sizeof(int));
    int*   bsum      = (int*)carve(256 * sizeof(int));
    int*   colsorted = (int*)carve((size_t)nE * sizeof(int));
    float* out       = (float*)d_out;

    unsigned short* Fq = F;
    unsigned short* Fk = F + 16384;
    unsigned short* Fv = F + 32768;

    dim3 blk(256);
    const int nbScan = (n + 1023) / 1024;            // 98 <= 256
    const int nbE8   = ((nE + 1023) / 1024) * 8;     // sliced edge blocks
    const int nbQ    = (n + 127) / 128;
    const int nbM    = (m + 127) / 128;

    // 1) zero counters
    hipMemsetAsync(cnt, 0, (size_t)(n + 1) * sizeof(int), stream);
    // 2) hist || prepack
    fused_pre_kernel<<<dim3(nbE8 + 192), blk, 0, stream>>>(
        erows, cnt, nE, n, nbE8, Wq, Wk, Wv, F);
    // 3) block sums
    scan_bsum_kernel<<<dim3(nbScan), blk, 0, stream>>>(cnt, bsum, n);
    // 4) rowptr + cur (inline boff re-scan)
    scan_write2_kernel<<<dim3(nbScan), blk, 0, stream>>>(cnt, bsum, nbScan, rowptr, cur, n);
    // 5) scatter || proj_q || proj_kv (LDS-free)
    fused_mid_kernel<<<dim3(nbE8 + nbQ + nbM), blk, 0, stream>>>(
        erows, ecols, cur, colsorted, nE, nbE8,
        query, memory, Fq, bq, q, Fk, bk, Fv, bv, kv, n, m, nbQ);
    // 6) aggregation (writes all outputs; no out memset needed)
    agg_kernel<<<dim3((n * 64 + 255) / 256), blk, 0, stream>>>(q, kv, rowptr, colsorted, out, n);
}